// Round 1
// baseline (781.538 us; speedup 1.0000x reference)
//
#include <hip/hip_runtime.h>

#define TOKENS 4096
#define IN_F   8192
#define OUT_F  8192

typedef int v4i __attribute__((ext_vector_type(4)));

__device__ __forceinline__ void gload_lds16(const void* g, void* l) {
    __builtin_amdgcn_global_load_lds(
        (const __attribute__((address_space(1))) void*)g,
        (__attribute__((address_space(3))) void*)l, 16, 0, 0);
}

// ---------------- Kernel 1: per-row absmax + int8 quantize ----------------
__global__ __launch_bounds__(256) void quant_kernel(const float* __restrict__ x,
                                                    signed char* __restrict__ xq,
                                                    float* __restrict__ recip_s) {
    const int row = blockIdx.x;
    const int t   = threadIdx.x;
    const float4* xr = (const float4*)(x + (size_t)row * IN_F);
    float4 v[8];
    float m = 0.f;
#pragma unroll
    for (int i = 0; i < 8; ++i) {
        v[i] = xr[t + 256 * i];
        m = fmaxf(m, fmaxf(fmaxf(fabsf(v[i].x), fabsf(v[i].y)),
                           fmaxf(fabsf(v[i].z), fabsf(v[i].w))));
    }
#pragma unroll
    for (int off = 32; off > 0; off >>= 1)
        m = fmaxf(m, __shfl_xor(m, off));
    __shared__ float wmax[4];
    if ((t & 63) == 0) wmax[t >> 6] = m;
    __syncthreads();
    m = fmaxf(fmaxf(wmax[0], wmax[1]), fmaxf(wmax[2], wmax[3]));
    m = fmaxf(m, 1e-5f);
    const float s = 127.0f / m;          // matches ref: s = 127/clip(max,1e-5)
    if (t == 0) recip_s[row] = m / 127.0f;
    unsigned int* out = (unsigned int*)(xq + (size_t)row * IN_F);
#pragma unroll
    for (int i = 0; i < 8; ++i) {
        int a = (int)fminf(fmaxf(rintf(v[i].x * s), -128.f), 127.f);
        int b = (int)fminf(fmaxf(rintf(v[i].y * s), -128.f), 127.f);
        int c = (int)fminf(fmaxf(rintf(v[i].z * s), -128.f), 127.f);
        int d = (int)fminf(fmaxf(rintf(v[i].w * s), -128.f), 127.f);
        out[t + 256 * i] = (a & 255) | ((b & 255) << 8) | ((c & 255) << 16) | ((d & 255) << 24);
    }
}

// ---------------- Kernel 2: weight int32 {0,1} -> int8 ----------------
__global__ __launch_bounds__(256) void pack_w(const int* __restrict__ w,
                                              signed char* __restrict__ w8) {
    const size_t idx = (size_t)blockIdx.x * 256 + threadIdx.x;  // 16 elems/thread
    const int4* wp = (const int4*)w;
    const size_t base = idx * 4;
    int4 a = wp[base], b = wp[base + 1], c = wp[base + 2], d = wp[base + 3];
    uint4 o;
    o.x = (a.x & 255) | ((a.y & 255) << 8) | ((a.z & 255) << 16) | ((a.w & 255) << 24);
    o.y = (b.x & 255) | ((b.y & 255) << 8) | ((b.z & 255) << 16) | ((b.w & 255) << 24);
    o.z = (c.x & 255) | ((c.y & 255) << 8) | ((c.z & 255) << 16) | ((c.w & 255) << 24);
    o.w = (d.x & 255) | ((d.y & 255) << 8) | ((d.z & 255) << 16) | ((d.w & 255) << 24);
    ((uint4*)w8)[idx] = o;
}

// ---------------- Kernel 3: i8 GEMM, 128x128 tile, BK=64 ----------------
// A = xq [M,K], B = w8 [N,K] (weight is already N-major over K), C = out [M,N]
__global__ __launch_bounds__(256) void gemm_kernel(const signed char* __restrict__ A,
                                                   const signed char* __restrict__ B,
                                                   const float* __restrict__ recip_s,
                                                   const float* __restrict__ wscale,
                                                   const float* __restrict__ bias,
                                                   float* __restrict__ out) {
    __shared__ signed char As[128 * 64];
    __shared__ signed char Bs[128 * 64];
    const int t    = threadIdx.x;
    const int wave = t >> 6;
    const int lane = t & 63;
    const int m0 = blockIdx.y * 128;
    const int n0 = blockIdx.x * 128;
    const int wm = (wave >> 1) * 64;   // wave row offset in tile
    const int wn = (wave & 1) * 64;    // wave col offset in tile

    v4i acc[4][4] = {};

    // staging: 256 threads x 16B = 4KB per call -> 2 calls per 8KB tile
    const int rowS = t >> 2;          // 0..63
    const int colS = (t & 3) * 16;    // byte offset in 64B row
    const signed char* gA = A + (size_t)(m0 + rowS) * IN_F + colS;
    const signed char* gB = B + (size_t)(n0 + rowS) * IN_F + colS;
    signed char* lA = As + t * 16;    // contiguous: row*64+col == t*16
    signed char* lB = Bs + t * 16;

    const int r16 = lane & 15;
    const int q   = lane >> 4;

    for (int k0 = 0; k0 < IN_F; k0 += 64) {
        gload_lds16(gA + k0, lA);
        gload_lds16(gA + (size_t)64 * IN_F + k0, lA + 4096);
        gload_lds16(gB + k0, lB);
        gload_lds16(gB + (size_t)64 * IN_F + k0, lB + 4096);
        __syncthreads();

        v4i a[4], b[4];
#pragma unroll
        for (int i = 0; i < 4; ++i)
            a[i] = *(const v4i*)(As + (wm + i * 16 + r16) * 64 + q * 16);
#pragma unroll
        for (int j = 0; j < 4; ++j)
            b[j] = *(const v4i*)(Bs + (wn + j * 16 + r16) * 64 + q * 16);
#pragma unroll
        for (int i = 0; i < 4; ++i)
#pragma unroll
            for (int j = 0; j < 4; ++j)
                acc[i][j] = __builtin_amdgcn_mfma_i32_16x16x64_i8(a[i], b[j], acc[i][j], 0, 0, 0);
        __syncthreads();
    }

    const float rws = 1.0f / wscale[0];
#pragma unroll
    for (int i = 0; i < 4; ++i) {
#pragma unroll
        for (int r = 0; r < 4; ++r) {
            const int row = m0 + wm + i * 16 + q * 4 + r;
            const float rs = recip_s[row] * rws;
#pragma unroll
            for (int j = 0; j < 4; ++j) {
                const int col = n0 + wn + j * 16 + r16;
                out[(size_t)row * OUT_F + col] = (float)acc[i][j][r] * rs + bias[col];
            }
        }
    }
}

extern "C" void kernel_launch(void* const* d_in, const int* in_sizes, int n_in,
                              void* d_out, int out_size, void* d_ws, size_t ws_size,
                              hipStream_t stream) {
    const float* x      = (const float*)d_in[0];
    const int*   w      = (const int*)d_in[1];
    const float* wscale = (const float*)d_in[2];
    const float* bias   = (const float*)d_in[3];
    float* out = (float*)d_out;

    signed char* xq = (signed char*)d_ws;                          // 32 MB
    signed char* w8 = xq + (size_t)TOKENS * IN_F;                  // 64 MB
    float* recip_s  = (float*)(w8 + (size_t)OUT_F * IN_F);         // 16 KB

    quant_kernel<<<TOKENS, 256, 0, stream>>>(x, xq, recip_s);
    pack_w<<<(int)(((size_t)OUT_F * IN_F) / 16 / 256), 256, 0, stream>>>(w, w8);
    dim3 grid(OUT_F / 128, TOKENS / 128);
    gemm_kernel<<<grid, 256, 0, stream>>>(xq, w8, recip_s, wscale, bias, out);
}

// Round 2
// 736.358 us; speedup vs baseline: 1.0614x; 1.0614x over previous
//
#include <hip/hip_runtime.h>

#define TOKENS 4096
#define IN_F   8192
#define OUT_F  8192

typedef int v4i __attribute__((ext_vector_type(4)));

__device__ __forceinline__ void gload_lds16(const void* g, void* l) {
    __builtin_amdgcn_global_load_lds(
        (const __attribute__((address_space(1))) void*)g,
        (__attribute__((address_space(3))) void*)l, 16, 0, 0);
}

// ---------------- Kernel 1: per-row absmax + int8 quantize ----------------
__global__ __launch_bounds__(256) void quant_kernel(const float* __restrict__ x,
                                                    signed char* __restrict__ xq,
                                                    float* __restrict__ recip_s) {
    const int row = blockIdx.x;
    const int t   = threadIdx.x;
    const float4* xr = (const float4*)(x + (size_t)row * IN_F);
    float4 v[8];
    float m = 0.f;
#pragma unroll
    for (int i = 0; i < 8; ++i) {
        v[i] = xr[t + 256 * i];
        m = fmaxf(m, fmaxf(fmaxf(fabsf(v[i].x), fabsf(v[i].y)),
                           fmaxf(fabsf(v[i].z), fabsf(v[i].w))));
    }
#pragma unroll
    for (int off = 32; off > 0; off >>= 1)
        m = fmaxf(m, __shfl_xor(m, off));
    __shared__ float wmax[4];
    if ((t & 63) == 0) wmax[t >> 6] = m;
    __syncthreads();
    m = fmaxf(fmaxf(wmax[0], wmax[1]), fmaxf(wmax[2], wmax[3]));
    m = fmaxf(m, 1e-5f);
    const float s = 127.0f / m;          // matches ref: s = 127/clip(max,1e-5)
    if (t == 0) recip_s[row] = m / 127.0f;
    unsigned int* out = (unsigned int*)(xq + (size_t)row * IN_F);
#pragma unroll
    for (int i = 0; i < 8; ++i) {
        int a = (int)fminf(fmaxf(rintf(v[i].x * s), -128.f), 127.f);
        int b = (int)fminf(fmaxf(rintf(v[i].y * s), -128.f), 127.f);
        int c = (int)fminf(fmaxf(rintf(v[i].z * s), -128.f), 127.f);
        int d = (int)fminf(fmaxf(rintf(v[i].w * s), -128.f), 127.f);
        out[t + 256 * i] = (a & 255) | ((b & 255) << 8) | ((c & 255) << 16) | ((d & 255) << 24);
    }
}

// ---------------- Kernel 2: weight int32 {0,1} -> int8 ----------------
// Fully coalesced: each thread 1x int4 load -> 1x uint store.
__global__ __launch_bounds__(256) void pack_w(const int* __restrict__ w,
                                              unsigned int* __restrict__ w8) {
    const size_t idx = (size_t)blockIdx.x * 256 + threadIdx.x;
    int4 a = ((const int4*)w)[idx];
    w8[idx] = (a.x & 255) | ((a.y & 255) << 8) | ((a.z & 255) << 16) | ((a.w & 255) << 24);
}

// ---------------- Kernel 3: i8 GEMM, 128x256 tile, BK=64, swizzled LDS ----
// A = xq [M,K], B = w8 [N,K], C = out [M,N]
// LDS chunk swizzle: 16B chunk c of row r stored at position c ^ ((r>>1)&3).
// Applied at staging (permute global source addr) and at fragment reads.
__global__ __launch_bounds__(256, 2) void gemm_kernel(const signed char* __restrict__ A,
                                                      const signed char* __restrict__ B,
                                                      const float* __restrict__ recip_s,
                                                      const float* __restrict__ wscale,
                                                      const float* __restrict__ bias,
                                                      float* __restrict__ out) {
    __shared__ signed char As[128 * 64];   // 8 KB
    __shared__ signed char Bs[256 * 64];   // 16 KB
    const int t    = threadIdx.x;
    const int wave = t >> 6;
    const int lane = t & 63;
    const int m0 = blockIdx.y * 128;
    const int n0 = blockIdx.x * 256;
    const int wm = (wave >> 1) * 64;    // wave row offset (M)
    const int wn = (wave & 1) * 128;    // wave col offset (N)

    v4i acc[4][8] = {};

    // staging: 256 threads x 16B = 4KB per call (64 rows of 64B)
    const int rowS = t >> 2;                       // 0..63
    const int colS = ((t & 3) ^ ((t >> 3) & 3)) * 16;  // swizzled source chunk
    const signed char* gA = A + (size_t)(m0 + rowS) * IN_F + colS;
    const signed char* gB = B + (size_t)(n0 + rowS) * IN_F + colS;
    signed char* lA = As + t * 16;                 // linear dest (HW constraint)
    signed char* lB = Bs + t * 16;

    const int r16 = lane & 15;
    const int q   = lane >> 4;
    const int cOff = ((q ^ ((r16 >> 1) & 3)) * 16);  // swizzled read chunk

    for (int k0 = 0; k0 < IN_F; k0 += 64) {
        gload_lds16(gA + k0, lA);
        gload_lds16(gA + (size_t)64 * IN_F + k0, lA + 4096);
        gload_lds16(gB + k0, lB);
        gload_lds16(gB + (size_t)64 * IN_F + k0, lB + 4096);
        gload_lds16(gB + (size_t)128 * IN_F + k0, lB + 8192);
        gload_lds16(gB + (size_t)192 * IN_F + k0, lB + 12288);
        __syncthreads();

        v4i a[4], b[8];
#pragma unroll
        for (int i = 0; i < 4; ++i)
            a[i] = *(const v4i*)(As + (wm + i * 16 + r16) * 64 + cOff);
#pragma unroll
        for (int j = 0; j < 8; ++j)
            b[j] = *(const v4i*)(Bs + (wn + j * 16 + r16) * 64 + cOff);
#pragma unroll
        for (int i = 0; i < 4; ++i)
#pragma unroll
            for (int j = 0; j < 8; ++j)
                acc[i][j] = __builtin_amdgcn_mfma_i32_16x16x64_i8(a[i], b[j], acc[i][j], 0, 0, 0);
        __syncthreads();
    }

    const float rws = 1.0f / wscale[0];
#pragma unroll
    for (int i = 0; i < 4; ++i) {
#pragma unroll
        for (int r = 0; r < 4; ++r) {
            const int row = m0 + wm + i * 16 + q * 4 + r;
            const float rs = recip_s[row] * rws;
#pragma unroll
            for (int j = 0; j < 8; ++j) {
                const int col = n0 + wn + j * 16 + r16;
                out[(size_t)row * OUT_F + col] = (float)acc[i][j][r] * rs + bias[col];
            }
        }
    }
}

extern "C" void kernel_launch(void* const* d_in, const int* in_sizes, int n_in,
                              void* d_out, int out_size, void* d_ws, size_t ws_size,
                              hipStream_t stream) {
    const float* x      = (const float*)d_in[0];
    const int*   w      = (const int*)d_in[1];
    const float* wscale = (const float*)d_in[2];
    const float* bias   = (const float*)d_in[3];
    float* out = (float*)d_out;

    signed char* xq = (signed char*)d_ws;                          // 32 MB
    signed char* w8 = xq + (size_t)TOKENS * IN_F;                  // 64 MB
    float* recip_s  = (float*)(w8 + (size_t)OUT_F * IN_F);         // 16 KB

    quant_kernel<<<TOKENS, 256, 0, stream>>>(x, xq, recip_s);
    pack_w<<<(int)(((size_t)OUT_F * IN_F) / 4 / 256), 256, 0, stream>>>(w, (unsigned int*)w8);
    dim3 grid(OUT_F / 256, TOKENS / 128);
    gemm_kernel<<<grid, 256, 0, stream>>>(xq, w8, recip_s, wscale, bias, out);
}